// Round 1
// baseline (136.891 us; speedup 1.0000x reference)
//
#include <hip/hip_runtime.h>
#include <hip/hip_bf16.h>
#include <stdint.h>

// ---- problem constants ----
#define M_TOT 12288   // B*T = 48*256
#define K_DIM 1024
#define N_DIM 1024

typedef __attribute__((ext_vector_type(8))) __bf16 bf16x8;
typedef __attribute__((ext_vector_type(4))) float  f32x4;

// ---------------------------------------------------------------------------
// Kernel 1: W[do][di] = sum_r H[r,k,s] * B[r,j,i],  do=k*32+j, di=s*32+i
// H[r, kb*8+k8, sb*8+s8] = sign[kb][sb] * A_stack[r, comp[kb][sb], k8, s8]
// ---------------------------------------------------------------------------
__global__ __launch_bounds__(256)
void make_w(const float* __restrict__ A4,   // [8][4][8][8]
            const float* __restrict__ Bs,   // [8][32][32]
            __bf16* __restrict__ W)         // [1024][1024], di contiguous
{
    int idx = blockIdx.x * 256 + threadIdx.x;   // 0 .. 1024*1024-1
    int dout = idx >> 10;
    int din  = idx & 1023;
    int k = dout >> 5, j = dout & 31;
    int s = din  >> 5, i = din  & 31;
    int kb = k >> 3, k8 = k & 7;
    int sb = s >> 3, s8 = s & 7;

    const int   comp[4][4] = {{0,1,2,3},{1,0,3,2},{2,3,0,1},{3,2,1,0}};
    const float sgn [4][4] = {{1.f,-1.f,-1.f,-1.f},
                              {1.f, 1.f,-1.f, 1.f},
                              {1.f, 1.f, 1.f,-1.f},
                              {1.f,-1.f, 1.f, 1.f}};
    int   c  = comp[kb][sb];
    float sg = sgn [kb][sb];

    float acc = 0.f;
    #pragma unroll
    for (int r = 0; r < 8; ++r) {
        float h = A4[((r*4 + c)*8 + k8)*8 + s8];
        float b = Bs[(r*32 + j)*32 + i];
        acc += h * b;
    }
    W[idx] = (__bf16)(sg * acc);
}

// ---------------------------------------------------------------------------
// Kernel 2: x f32 -> bf16 (8 elems / thread)
// ---------------------------------------------------------------------------
__global__ __launch_bounds__(256)
void cvt_x(const float* __restrict__ X, __bf16* __restrict__ Xb)
{
    size_t t = (size_t)blockIdx.x * 256 + threadIdx.x;
    const float4* x4 = (const float4*)X;
    float4 a = x4[2*t + 0];
    float4 b = x4[2*t + 1];
    bf16x8 v;
    v[0] = (__bf16)a.x; v[1] = (__bf16)a.y; v[2] = (__bf16)a.z; v[3] = (__bf16)a.w;
    v[4] = (__bf16)b.x; v[5] = (__bf16)b.y; v[6] = (__bf16)b.z; v[7] = (__bf16)b.w;
    *(bf16x8*)&Xb[t * 8] = v;
}

// ---------------------------------------------------------------------------
// Kernel 3: C[M][N] = A[M][K] * BT[N][K]^T + bias   (bf16 in, f32 out)
// m97 structure: 128x128 tile, BK=32, 4 waves (2x2), 16x16x32 MFMA,
// global_load_lds width=16 staging, linear LDS tiles.
// ---------------------------------------------------------------------------
#define BM 128
#define BN 128
#define BK 32

__device__ __forceinline__ void gl_lds16(const void* g, void* l)
{
    __builtin_amdgcn_global_load_lds(
        (const __attribute__((address_space(1))) void*)g,
        (__attribute__((address_space(3))) void*)l,
        16, 0, 0);
}

__global__ __launch_bounds__(256)
void gemm_bt(const __bf16* __restrict__ A,   // [M][K]
             const __bf16* __restrict__ BT,  // [N][K]
             const float*  __restrict__ bias,
             float* __restrict__ C)          // [M][N]
{
    __shared__ __align__(16) __bf16 Alds[BM * BK];  // 8 KB
    __shared__ __align__(16) __bf16 Blds[BN * BK];  // 8 KB

    const int tid  = threadIdx.x;
    const int wave = tid >> 6;
    const int lane = tid & 63;

    const int brow = blockIdx.y * BM;
    const int bcol = blockIdx.x * BN;

    const int wm = (wave >> 1) * 64;   // wave's row offset within tile
    const int wn = (wave & 1)  * 64;   // wave's col offset within tile

    f32x4 acc[4][4];
    #pragma unroll
    for (int i = 0; i < 4; ++i)
        #pragma unroll
        for (int jj = 0; jj < 4; ++jj)
            acc[i][jj] = (f32x4){0.f, 0.f, 0.f, 0.f};

    const int fr = lane & 15;      // fragment row (A) / col (B)
    const int kq = lane >> 4;      // k quarter: k = kq*8 .. kq*8+7

    char* AldsC = (char*)Alds;
    char* BldsC = (char*)Blds;

    for (int k0 = 0; k0 < K_DIM; k0 += BK) {
        // ---- stage A,B tiles: 8192 B each; per wave 2 issues of 1024 B ----
        #pragma unroll
        for (int q = 0; q < 2; ++q) {
            int ofs  = wave * 2048 + q * 1024 + lane * 16;  // byte off in tile
            int row  = ofs >> 6;       // 64 B per row (32 bf16)
            int colb = ofs & 63;
            gl_lds16((const char*)A  + ((size_t)(brow + row) * K_DIM + k0) * 2 + colb,
                     AldsC + wave * 2048 + q * 1024);
            gl_lds16((const char*)BT + ((size_t)(bcol + row) * K_DIM + k0) * 2 + colb,
                     BldsC + wave * 2048 + q * 1024);
        }
        __syncthreads();   // compiler drains vmcnt before s_barrier

        // ---- fragments + MFMA ----
        bf16x8 af[4], bfr[4];
        #pragma unroll
        for (int mi = 0; mi < 4; ++mi)
            af[mi] = *(const bf16x8*)&Alds[(wm + mi*16 + fr) * BK + kq * 8];
        #pragma unroll
        for (int ni = 0; ni < 4; ++ni)
            bfr[ni] = *(const bf16x8*)&Blds[(wn + ni*16 + fr) * BK + kq * 8];

        #pragma unroll
        for (int mi = 0; mi < 4; ++mi)
            #pragma unroll
            for (int ni = 0; ni < 4; ++ni)
                acc[mi][ni] = __builtin_amdgcn_mfma_f32_16x16x32_bf16(
                    af[mi], bfr[ni], acc[mi][ni], 0, 0, 0);

        __syncthreads();
    }

    // ---- epilogue: C/D layout col = lane&15, row = (lane>>4)*4 + reg ----
    #pragma unroll
    for (int mi = 0; mi < 4; ++mi) {
        int r0 = brow + wm + mi*16 + (lane >> 4) * 4;
        #pragma unroll
        for (int ni = 0; ni < 4; ++ni) {
            int c0 = bcol + wn + ni*16 + (lane & 15);
            float bv = bias[c0];
            #pragma unroll
            for (int j = 0; j < 4; ++j)
                C[(size_t)(r0 + j) * N_DIM + c0] = acc[mi][ni][j] + bv;
        }
    }
}

// ---------------------------------------------------------------------------
extern "C" void kernel_launch(void* const* d_in, const int* in_sizes, int n_in,
                              void* d_out, int out_size, void* d_ws, size_t ws_size,
                              hipStream_t stream)
{
    const float* x    = (const float*)d_in[0];   // [48][256][1024]
    const float* A4   = (const float*)d_in[1];   // [8][4][8][8]
    const float* Bs   = (const float*)d_in[2];   // [8][32][32]
    const float* bias = (const float*)d_in[3];   // [1024]
    float* out = (float*)d_out;

    __bf16* W  = (__bf16*)d_ws;                          // 2 MB
    __bf16* Xb = (__bf16*)((char*)d_ws + (size_t)(1<<21)); // 24 MB

    make_w<<<4096, 256, 0, stream>>>(A4, Bs, W);
    cvt_x<<<(M_TOT * K_DIM / 8 + 255) / 256, 256, 0, stream>>>(x, Xb);

    dim3 grid(N_DIM / BN, M_TOT / BM);   // 8 x 96 = 768 blocks
    gemm_bt<<<grid, 256, 0, stream>>>(Xb, W, bias, out);
}

// Round 2
// 133.467 us; speedup vs baseline: 1.0257x; 1.0257x over previous
//
#include <hip/hip_runtime.h>
#include <hip/hip_bf16.h>
#include <stdint.h>

// ---- problem constants ----
#define M_TOT 12288   // B*T = 48*256
#define K_DIM 1024
#define N_DIM 1024
#define NTILE 16      // K_DIM / 64

typedef __attribute__((ext_vector_type(8))) __bf16 bf16x8;
typedef __attribute__((ext_vector_type(4))) float  f32x4;

// ---------------------------------------------------------------------------
// Kernel 1: W[do][di] = sum_r H[r,k,s] * B[r,j,i],  do=k*32+j, di=s*32+i
// ---------------------------------------------------------------------------
__global__ __launch_bounds__(256)
void make_w(const float* __restrict__ A4,   // [8][4][8][8]
            const float* __restrict__ Bs,   // [8][32][32]
            __bf16* __restrict__ W)         // [1024][1024], di contiguous
{
    int idx = blockIdx.x * 256 + threadIdx.x;
    int dout = idx >> 10;
    int din  = idx & 1023;
    int k = dout >> 5, j = dout & 31;
    int s = din  >> 5, i = din  & 31;
    int kb = k >> 3, k8 = k & 7;
    int sb = s >> 3, s8 = s & 7;

    const int   comp[4][4] = {{0,1,2,3},{1,0,3,2},{2,3,0,1},{3,2,1,0}};
    const float sgn [4][4] = {{1.f,-1.f,-1.f,-1.f},
                              {1.f, 1.f,-1.f, 1.f},
                              {1.f, 1.f, 1.f,-1.f},
                              {1.f,-1.f, 1.f, 1.f}};
    int   c  = comp[kb][sb];
    float sg = sgn [kb][sb];

    float acc = 0.f;
    #pragma unroll
    for (int r = 0; r < 8; ++r) {
        float h = A4[((r*4 + c)*8 + k8)*8 + s8];
        float b = Bs[(r*32 + j)*32 + i];
        acc += h * b;
    }
    W[idx] = (__bf16)(sg * acc);
}

// ---------------------------------------------------------------------------
// Kernel 2: x f32 -> bf16 (8 elems / thread)
// ---------------------------------------------------------------------------
__global__ __launch_bounds__(256)
void cvt_x(const float* __restrict__ X, __bf16* __restrict__ Xb)
{
    size_t t = (size_t)blockIdx.x * 256 + threadIdx.x;
    const float4* x4 = (const float4*)X;
    float4 a = x4[2*t + 0];
    float4 b = x4[2*t + 1];
    bf16x8 v;
    v[0] = (__bf16)a.x; v[1] = (__bf16)a.y; v[2] = (__bf16)a.z; v[3] = (__bf16)a.w;
    v[4] = (__bf16)b.x; v[5] = (__bf16)b.y; v[6] = (__bf16)b.z; v[7] = (__bf16)b.w;
    *(bf16x8*)&Xb[t * 8] = v;
}

// ---------------------------------------------------------------------------
// Kernel 3: 256x256-tile 8-phase GEMM, BK=64, 8 waves (2M x 4N), 128 KiB LDS.
// C[M][N] = A[M][K] * BT[N][K]^T + bias  (bf16 in, f32 out)
// LDS per buffer: [A-mh0 16K][A-mh1 16K][B-nh0 16K][B-nh1 16K]
//   A-mh half = rows {mh*64..+63, 128+mh*64..+63} of the 256-row tile
//   B-nh half = W rows {g*64+nh*32..+31 : g=0..3}
// Each half stored [128][64] bf16 (128 B rows), content swizzled:
//   element(rwh,colb) at byte rwh*128 + (colb ^ ((rwh&7)<<4))
// global_load_lds writes linearly -> global SOURCE address is pre-unswizzled.
// ---------------------------------------------------------------------------
__device__ __forceinline__ void gl_lds16(const void* g, void* l)
{
    __builtin_amdgcn_global_load_lds(
        (const __attribute__((address_space(1))) void*)g,
        (__attribute__((address_space(3))) void*)l,
        16, 0, 0);
}

#define PHASE_MFMA(MH, NH, BF)                                                  \
    __builtin_amdgcn_s_barrier();                                               \
    asm volatile("s_waitcnt lgkmcnt(0)" ::: "memory");                          \
    __builtin_amdgcn_sched_barrier(0);                                          \
    __builtin_amdgcn_s_setprio(1);                                              \
    _Pragma("unroll")                                                           \
    for (int mi = 0; mi < 4; ++mi) {                                            \
        _Pragma("unroll")                                                       \
        for (int ni = 0; ni < 2; ++ni) {                                        \
            acc[(MH)*4+mi][(NH)*2+ni] = __builtin_amdgcn_mfma_f32_16x16x32_bf16(\
                aF[mi][0], BF[ni][0], acc[(MH)*4+mi][(NH)*2+ni], 0, 0, 0);      \
            acc[(MH)*4+mi][(NH)*2+ni] = __builtin_amdgcn_mfma_f32_16x16x32_bf16(\
                aF[mi][1], BF[ni][1], acc[(MH)*4+mi][(NH)*2+ni], 0, 0, 0);      \
        }                                                                       \
    }                                                                           \
    __builtin_amdgcn_s_setprio(0);                                              \
    __builtin_amdgcn_s_barrier();

__global__ __launch_bounds__(512, 2)
void gemm8p(const __bf16* __restrict__ A,   // [M][1024]
            const __bf16* __restrict__ BT,  // [1024][1024]  (W)
            const float*  __restrict__ bias,
            float* __restrict__ C)          // [M][1024]
{
    __shared__ __align__(16) char lds[131072];

    const int tid  = threadIdx.x;
    const int wave = tid >> 6;
    const int lane = tid & 63;

    // bijective XCD swizzle (192 % 8 == 0): each XCD gets 24 consecutive tiles
    int wg  = blockIdx.x;
    int swz = (wg & 7) * 24 + (wg >> 3);
    const int brow = (swz >> 2) * 256;   // 48 M-tiles
    const int bcol = (swz & 3)  * 256;   // 4  N-tiles

    const int mg = wave >> 2;    // m-group 0/1 (rows mg*128..+127)
    const int ng = wave & 3;     // n-group 0..3 (cols ng*64..+63)
    const int fr = lane & 15;
    const int kq = lane >> 4;

    f32x4 acc[8][4];
    #pragma unroll
    for (int i = 0; i < 8; ++i)
        #pragma unroll
        for (int j = 0; j < 4; ++j)
            acc[i][j] = (f32x4){0.f, 0.f, 0.f, 0.f};

    // ---- staging helpers (2 x gl_lds16 per thread per half-tile) ----
    auto stageA = [&](int ta, int mh) {
        if (ta >= NTILE) return;
        char* region = lds + (ta & 1) * 65536 + mh * 16384;
        #pragma unroll
        for (int q = 0; q < 2; ++q) {
            int s    = q * 8192 + tid * 16;
            int rwh  = s >> 7;
            int colb = (s & 127) ^ ((rwh & 7) << 4);     // inverse swizzle
            int absr = ((rwh >> 6) << 7) + mh * 64 + (rwh & 63);
            const char* src = (const char*)A +
                ((size_t)(brow + absr) * K_DIM + ta * 64) * 2 + colb;
            gl_lds16(src, region + q * 8192 + wave * 1024);
        }
    };
    auto stageB = [&](int ta, int nh) {
        if (ta >= NTILE) return;
        char* region = lds + (ta & 1) * 65536 + 32768 + nh * 16384;
        #pragma unroll
        for (int q = 0; q < 2; ++q) {
            int s    = q * 8192 + tid * 16;
            int rwh  = s >> 7;
            int colb = (s & 127) ^ ((rwh & 7) << 4);
            int absr = ((rwh >> 5) << 6) + nh * 32 + (rwh & 31);
            const char* src = (const char*)BT +
                ((size_t)(bcol + absr) * K_DIM + ta * 64) * 2 + colb;
            gl_lds16(src, region + q * 8192 + wave * 1024);
        }
    };

    bf16x8 aF[4][2], bF0[2][2], bF1[2][2];

    auto ldA = [&](int bufb, int mh) {
        const char* base = lds + bufb + mh * 16384;
        #pragma unroll
        for (int mi = 0; mi < 4; ++mi) {
            int rwh = mg * 64 + mi * 16 + fr;
            #pragma unroll
            for (int ks = 0; ks < 2; ++ks) {
                int col = (ks * 64 + kq * 16) ^ ((rwh & 7) << 4);
                aF[mi][ks] = *(const bf16x8*)(base + rwh * 128 + col);
            }
        }
    };
    auto ldB = [&](bf16x8 (&bF)[2][2], int bufb, int nh) {
        const char* base = lds + bufb + 32768 + nh * 16384;
        #pragma unroll
        for (int ni = 0; ni < 2; ++ni) {
            int rwh = ng * 32 + ni * 16 + fr;
            #pragma unroll
            for (int ks = 0; ks < 2; ++ks) {
                int col = (ks * 64 + kq * 16) ^ ((rwh & 7) << 4);
                bF[ni][ks] = *(const bf16x8*)(base + rwh * 128 + col);
            }
        }
    };

    // ---- prologue: tile0 fully + tile1 A-halves; keep 4 loads in flight ----
    stageA(0, 0); stageA(0, 1); stageB(0, 0); stageB(0, 1);
    stageA(1, 0); stageA(1, 1);
    asm volatile("s_waitcnt vmcnt(4)" ::: "memory");
    __builtin_amdgcn_s_barrier();

    // ---- main loop: 16 K-tiles x 4 phases ----
    for (int t = 0; t < NTILE; ++t) {
        const int bufb = (t & 1) * 65536;

        // PH0: quadrant (mh0, nh0)
        ldA(bufb, 0);
        ldB(bF0, bufb, 0);
        stageB(t + 1, 0);
        PHASE_MFMA(0, 0, bF0)

        // PH1: quadrant (mh0, nh1)
        ldB(bF1, bufb, 1);
        stageB(t + 1, 1);
        PHASE_MFMA(0, 1, bF1)

        // PH2: quadrant (mh1, nh1)
        ldA(bufb, 1);
        stageA(t + 2, 0);
        PHASE_MFMA(1, 1, bF1)

        // PH3: quadrant (mh1, nh0) — no ds_reads, reuse aF + bF0
        stageA(t + 2, 1);
        __builtin_amdgcn_s_barrier();
        __builtin_amdgcn_s_setprio(1);
        #pragma unroll
        for (int mi = 0; mi < 4; ++mi) {
            #pragma unroll
            for (int ni = 0; ni < 2; ++ni) {
                acc[4+mi][ni] = __builtin_amdgcn_mfma_f32_16x16x32_bf16(
                    aF[mi][0], bF0[ni][0], acc[4+mi][ni], 0, 0, 0);
                acc[4+mi][ni] = __builtin_amdgcn_mfma_f32_16x16x32_bf16(
                    aF[mi][1], bF0[ni][1], acc[4+mi][ni], 0, 0, 0);
            }
        }
        __builtin_amdgcn_s_setprio(0);
        // counted drain: keep (t+2).A half-tiles in flight; tail drains fully
        if (t < NTILE - 2) {
            asm volatile("s_waitcnt vmcnt(4)" ::: "memory");
        } else {
            asm volatile("s_waitcnt vmcnt(0)" ::: "memory");
        }
        __builtin_amdgcn_s_barrier();
    }

    // ---- epilogue ----
    #pragma unroll
    for (int mf = 0; mf < 8; ++mf) {
        int r0 = brow + mg * 128 + mf * 16 + kq * 4;
        #pragma unroll
        for (int nf = 0; nf < 4; ++nf) {
            int c0 = bcol + ng * 64 + nf * 16 + fr;
            float bv = bias[c0];
            #pragma unroll
            for (int j = 0; j < 4; ++j)
                C[(size_t)(r0 + j) * N_DIM + c0] = acc[mf][nf][j] + bv;
        }
    }
}

// ---------------------------------------------------------------------------
extern "C" void kernel_launch(void* const* d_in, const int* in_sizes, int n_in,
                              void* d_out, int out_size, void* d_ws, size_t ws_size,
                              hipStream_t stream)
{
    const float* x    = (const float*)d_in[0];   // [48][256][1024]
    const float* A4   = (const float*)d_in[1];   // [8][4][8][8]
    const float* Bs   = (const float*)d_in[2];   // [8][32][32]
    const float* bias = (const float*)d_in[3];   // [1024]
    float* out = (float*)d_out;

    __bf16* W  = (__bf16*)d_ws;                            // 2 MB
    __bf16* Xb = (__bf16*)((char*)d_ws + (size_t)(1<<21)); // 24 MB

    make_w<<<4096, 256, 0, stream>>>(A4, Bs, W);
    cvt_x<<<(M_TOT * K_DIM / 8 + 255) / 256, 256, 0, stream>>>(x, Xb);

    gemm8p<<<192, 512, 0, stream>>>(Xb, W, bias, out);
}

// Round 3
// 129.727 us; speedup vs baseline: 1.0552x; 1.0288x over previous
//
#include <hip/hip_runtime.h>
#include <hip/hip_bf16.h>
#include <stdint.h>

// ---- problem constants ----
#define M_TOT 12288   // B*T = 48*256
#define K_DIM 1024
#define N_DIM 1024
#define NTILE 16      // K_DIM / 64

// GEMM geometry: BM=192, BN=256, BK=64, 8 waves (2M x 4N), grid 64x4=256 blocks
#define LDSBUF 57344  // per-buffer bytes: A 24576 + B 2x16384

typedef __attribute__((ext_vector_type(8))) __bf16 bf16x8;
typedef __attribute__((ext_vector_type(4))) float  f32x4;

// ---------------------------------------------------------------------------
// Kernel 1: W[do][di] = sum_r H[r,k,s] * B[r,j,i],  do=k*32+j, di=s*32+i
// ---------------------------------------------------------------------------
__global__ __launch_bounds__(256)
void make_w(const float* __restrict__ A4,   // [8][4][8][8]
            const float* __restrict__ Bs,   // [8][32][32]
            __bf16* __restrict__ W)         // [1024][1024], di contiguous
{
    int idx = blockIdx.x * 256 + threadIdx.x;
    int dout = idx >> 10;
    int din  = idx & 1023;
    int k = dout >> 5, j = dout & 31;
    int s = din  >> 5, i = din  & 31;
    int kb = k >> 3, k8 = k & 7;
    int sb = s >> 3, s8 = s & 7;

    const int   comp[4][4] = {{0,1,2,3},{1,0,3,2},{2,3,0,1},{3,2,1,0}};
    const float sgn [4][4] = {{1.f,-1.f,-1.f,-1.f},
                              {1.f, 1.f,-1.f, 1.f},
                              {1.f, 1.f, 1.f,-1.f},
                              {1.f,-1.f, 1.f, 1.f}};
    int   c  = comp[kb][sb];
    float sg = sgn [kb][sb];

    float acc = 0.f;
    #pragma unroll
    for (int r = 0; r < 8; ++r) {
        float h = A4[((r*4 + c)*8 + k8)*8 + s8];
        float b = Bs[(r*32 + j)*32 + i];
        acc += h * b;
    }
    W[idx] = (__bf16)(sg * acc);
}

// ---------------------------------------------------------------------------
// Kernel 2: x f32 -> bf16 (8 elems / thread)
// ---------------------------------------------------------------------------
__global__ __launch_bounds__(256)
void cvt_x(const float* __restrict__ X, __bf16* __restrict__ Xb)
{
    size_t t = (size_t)blockIdx.x * 256 + threadIdx.x;
    const float4* x4 = (const float4*)X;
    float4 a = x4[2*t + 0];
    float4 b = x4[2*t + 1];
    bf16x8 v;
    v[0] = (__bf16)a.x; v[1] = (__bf16)a.y; v[2] = (__bf16)a.z; v[3] = (__bf16)a.w;
    v[4] = (__bf16)b.x; v[5] = (__bf16)b.y; v[6] = (__bf16)b.z; v[7] = (__bf16)b.w;
    *(bf16x8*)&Xb[t * 8] = v;
}

// ---------------------------------------------------------------------------
// Kernel 3: 192x256-tile 8-phase GEMM, BK=64, 8 waves (2M x 4N), 112 KiB LDS,
// grid 256 blocks = exactly 1/CU (100% fill).
// C[M][N] = A[M][K] * BT[N][K]^T + bias  (bf16 in, f32 out)
// LDS per buffer: [A 24K : rows 0..191][B-nh0 16K][B-nh1 16K]
//   B-nh half = W rows {g*64+nh*32+r : g=0..3, r=0..31}, stored [128][64]
// Rows are 128 B; content swizzled: elem(row,colb) at row*128 + (colb ^ ((row&7)<<4)).
// global_load_lds writes linearly -> global SOURCE address pre-unswizzled.
// Phase order: PH0=(sub0,nh0) PH1=(sub0,nh1) PH2=(sub1,nh1) PH3=(sub1,nh0);
// A sub = 48-row half of each wave-group's 96 rows; A region of current buffer
// is fully dead after PH2, so stageA(t+2) issues at PH3.
// ---------------------------------------------------------------------------
__device__ __forceinline__ void gl_lds16(const void* g, void* l)
{
    __builtin_amdgcn_global_load_lds(
        (const __attribute__((address_space(1))) void*)g,
        (__attribute__((address_space(3))) void*)l,
        16, 0, 0);
}

#define PHASE_MFMA(SUB, NH, BF)                                                 \
    __builtin_amdgcn_s_barrier();                                               \
    asm volatile("s_waitcnt lgkmcnt(0)" ::: "memory");                          \
    __builtin_amdgcn_sched_barrier(0);                                          \
    __builtin_amdgcn_s_setprio(1);                                              \
    _Pragma("unroll")                                                           \
    for (int mi = 0; mi < 3; ++mi) {                                            \
        _Pragma("unroll")                                                       \
        for (int ni = 0; ni < 2; ++ni) {                                        \
            acc[(SUB)*3+mi][(NH)*2+ni] = __builtin_amdgcn_mfma_f32_16x16x32_bf16(\
                aF[mi][0], BF[ni][0], acc[(SUB)*3+mi][(NH)*2+ni], 0, 0, 0);     \
            acc[(SUB)*3+mi][(NH)*2+ni] = __builtin_amdgcn_mfma_f32_16x16x32_bf16(\
                aF[mi][1], BF[ni][1], acc[(SUB)*3+mi][(NH)*2+ni], 0, 0, 0);     \
        }                                                                       \
    }                                                                           \
    __builtin_amdgcn_s_setprio(0);                                              \
    __builtin_amdgcn_s_barrier();

__global__ __launch_bounds__(512, 2)
void gemm8p(const __bf16* __restrict__ A,   // [M][1024]
            const __bf16* __restrict__ BT,  // [1024][1024]  (W)
            const float*  __restrict__ bias,
            float* __restrict__ C)          // [M][1024]
{
    __shared__ __align__(16) char lds[2 * LDSBUF];

    const int tid  = threadIdx.x;
    const int wave = tid >> 6;
    const int lane = tid & 63;

    // bijective XCD swizzle (256 % 8 == 0): each XCD gets 32 consecutive tiles
    int wg  = blockIdx.x;
    int swz = (wg & 7) * 32 + (wg >> 3);
    const int brow = (swz >> 2) * 192;   // 64 M-tiles
    const int bcol = (swz & 3)  * 256;   // 4  N-tiles

    const int mg = wave >> 2;    // m-group 0/1 (rows mg*96..+95)
    const int ng = wave & 3;     // n-group 0..3 (cols ng*64..+63)
    const int fr = lane & 15;
    const int kq = lane >> 4;

    f32x4 acc[6][4];
    #pragma unroll
    for (int i = 0; i < 6; ++i)
        #pragma unroll
        for (int j = 0; j < 4; ++j)
            acc[i][j] = (f32x4){0.f, 0.f, 0.f, 0.f};

    // ---- staging helpers ----
    auto stageA = [&](int ta) {          // 3 x gl_lds16 / thread, 24 KB
        if (ta >= NTILE) return;
        char* region = lds + (ta & 1) * LDSBUF;
        #pragma unroll
        for (int q = 0; q < 3; ++q) {
            int s    = q * 8192 + tid * 16;
            int rwh  = s >> 7;                            // 0..191
            int colb = (s & 127) ^ ((rwh & 7) << 4);      // inverse swizzle
            const char* src = (const char*)A +
                ((size_t)(brow + rwh) * K_DIM + ta * 64) * 2 + colb;
            gl_lds16(src, region + q * 8192 + wave * 1024);
        }
    };
    auto stageB = [&](int ta, int nh) {  // 2 x gl_lds16 / thread, 16 KB
        if (ta >= NTILE) return;
        char* region = lds + (ta & 1) * LDSBUF + 24576 + nh * 16384;
        #pragma unroll
        for (int q = 0; q < 2; ++q) {
            int s    = q * 8192 + tid * 16;
            int rwh  = s >> 7;                            // 0..127
            int colb = (s & 127) ^ ((rwh & 7) << 4);
            int absr = ((rwh >> 5) << 6) + nh * 32 + (rwh & 31);
            const char* src = (const char*)BT +
                ((size_t)(bcol + absr) * K_DIM + ta * 64) * 2 + colb;
            gl_lds16(src, region + q * 8192 + wave * 1024);
        }
    };

    bf16x8 aF[3][2], bF0[2][2], bF1[2][2];

    auto ldA = [&](int bufb, int sub) {
        const char* base = lds + bufb;
        #pragma unroll
        for (int mi = 0; mi < 3; ++mi) {
            int rwh = mg * 96 + sub * 48 + mi * 16 + fr;
            #pragma unroll
            for (int ks = 0; ks < 2; ++ks) {
                int col = (ks * 64 + kq * 16) ^ ((rwh & 7) << 4);
                aF[mi][ks] = *(const bf16x8*)(base + rwh * 128 + col);
            }
        }
    };
    auto ldB = [&](bf16x8 (&bF)[2][2], int bufb, int nh) {
        const char* base = lds + bufb + 24576 + nh * 16384;
        #pragma unroll
        for (int ni = 0; ni < 2; ++ni) {
            int rwh = ng * 32 + ni * 16 + fr;
            #pragma unroll
            for (int ks = 0; ks < 2; ++ks) {
                int col = (ks * 64 + kq * 16) ^ ((rwh & 7) << 4);
                bF[ni][ks] = *(const bf16x8*)(base + rwh * 128 + col);
            }
        }
    };

    // ---- prologue: tile0 fully + tile1 A; keep A(1)'s 3 loads in flight ----
    stageA(0); stageB(0, 0); stageB(0, 1);
    stageA(1);
    asm volatile("s_waitcnt vmcnt(3)" ::: "memory");
    __builtin_amdgcn_s_barrier();

    // ---- main loop: 16 K-tiles x 4 phases ----
    for (int t = 0; t < NTILE; ++t) {
        const int bufb = (t & 1) * LDSBUF;

        // PH0: (sub0, nh0)
        ldA(bufb, 0);
        ldB(bF0, bufb, 0);
        stageB(t + 1, 0);
        PHASE_MFMA(0, 0, bF0)

        // PH1: (sub0, nh1)
        ldB(bF1, bufb, 1);
        stageB(t + 1, 1);
        PHASE_MFMA(0, 1, bF1)

        // PH2: (sub1, nh1) — reuse bF1
        ldA(bufb, 1);
        PHASE_MFMA(1, 1, bF1)

        // PH3: (sub1, nh0) — no ds_reads, reuse aF + bF0; stage A(t+2)
        stageA(t + 2);
        __builtin_amdgcn_s_barrier();
        __builtin_amdgcn_s_setprio(1);
        #pragma unroll
        for (int mi = 0; mi < 3; ++mi) {
            #pragma unroll
            for (int ni = 0; ni < 2; ++ni) {
                acc[3+mi][ni] = __builtin_amdgcn_mfma_f32_16x16x32_bf16(
                    aF[mi][0], bF0[ni][0], acc[3+mi][ni], 0, 0, 0);
                acc[3+mi][ni] = __builtin_amdgcn_mfma_f32_16x16x32_bf16(
                    aF[mi][1], bF0[ni][1], acc[3+mi][ni], 0, 0, 0);
            }
        }
        __builtin_amdgcn_s_setprio(0);
        // counted drain: tile t+1 complete, keep A(t+2)'s 3 loads in flight
        if (t < NTILE - 2) {
            asm volatile("s_waitcnt vmcnt(3)" ::: "memory");
        } else {
            asm volatile("s_waitcnt vmcnt(0)" ::: "memory");
        }
        __builtin_amdgcn_s_barrier();
    }

    // ---- epilogue ----
    #pragma unroll
    for (int mf = 0; mf < 6; ++mf) {
        int r0 = brow + mg * 96 + mf * 16 + kq * 4;
        #pragma unroll
        for (int nf = 0; nf < 4; ++nf) {
            int c0 = bcol + ng * 64 + nf * 16 + fr;
            float bv = bias[c0];
            #pragma unroll
            for (int j = 0; j < 4; ++j)
                C[(size_t)(r0 + j) * N_DIM + c0] = acc[mf][nf][j] + bv;
        }
    }
}

// ---------------------------------------------------------------------------
extern "C" void kernel_launch(void* const* d_in, const int* in_sizes, int n_in,
                              void* d_out, int out_size, void* d_ws, size_t ws_size,
                              hipStream_t stream)
{
    const float* x    = (const float*)d_in[0];   // [48][256][1024]
    const float* A4   = (const float*)d_in[1];   // [8][4][8][8]
    const float* Bs   = (const float*)d_in[2];   // [8][32][32]
    const float* bias = (const float*)d_in[3];   // [1024]
    float* out = (float*)d_out;

    __bf16* W  = (__bf16*)d_ws;                            // 2 MB
    __bf16* Xb = (__bf16*)((char*)d_ws + (size_t)(1<<21)); // 24 MB

    make_w<<<4096, 256, 0, stream>>>(A4, Bs, W);
    cvt_x<<<(M_TOT * K_DIM / 8 + 255) / 256, 256, 0, stream>>>(x, Xb);

    gemm8p<<<256, 512, 0, stream>>>(Xb, W, bias, out);
}